// Round 4
// baseline (424.336 us; speedup 1.0000x reference)
//
#include <hip/hip_runtime.h>
#include <hip/hip_bf16.h>

#define B_ 64
#define L_ 512
#define H_ 1024
#define A_ 1024

typedef short bf16x8 __attribute__((ext_vector_type(8)));
typedef float f32x4 __attribute__((ext_vector_type(4)));

__device__ __forceinline__ void gld16(const void* g, void* l) {
  __builtin_amdgcn_global_load_lds((const __attribute__((address_space(1))) void*)g,
                                   (__attribute__((address_space(3))) void*)l, 16, 0, 0);
}

// f32 -> bf16 RNE bit trick (cold paths)
__device__ __forceinline__ unsigned short f2bf(float f) {
  unsigned u = __builtin_bit_cast(unsigned, f);
  u = (u + 0x7fffu + ((u >> 16) & 1u)) >> 16;
  return (unsigned short)u;
}

// hot-path cast: compiler fuses pairs into v_cvt_pk_bf16_f32
__device__ __forceinline__ unsigned short cvtbf(float f) {
  __hip_bfloat16 b = __float2bfloat16(f);
  return __builtin_bit_cast(unsigned short, b);
}

// tanh(x) = 1 - 2/(exp(2x)+1), fast rcp (v_rcp_f32, ~1ulp -> invisible in bf16)
__device__ __forceinline__ float fast_tanh(float x) {
  float e = __expf(2.f * x);
  float r = __builtin_amdgcn_rcpf(e + 1.f);
  return __builtin_fmaf(-2.f, r, 1.f);
}

// ---------- K0: Wt[a][h] = bf16(W[h][a]) ----------
__global__ __launch_bounds__(256) void wtrans_kernel(const float* __restrict__ W,
                                                     unsigned short* __restrict__ Wt) {
  __shared__ float tile[32][33];
  int tx = threadIdx.x & 31, ty = threadIdx.x >> 5;  // 32 x 8
  int a0 = (blockIdx.x & 31) << 5, h0 = (blockIdx.x >> 5) << 5;
#pragma unroll
  for (int i = 0; i < 4; ++i) {
    int h = ty + i * 8;
    tile[h][tx] = W[(size_t)(h0 + h) * A_ + a0 + tx];
  }
  __syncthreads();
#pragma unroll
  for (int i = 0; i < 4; ++i) {
    int a = ty + i * 8;
    Wt[(size_t)(a0 + a) * H_ + h0 + tx] = f2bf(tile[tx][a]);
  }
}

// ---------- K1: Pb = bf16(tanh(X @ Wt^T) [* diag]) ----------
// Fused f32-A version, double-buffered LDS, one barrier per K-tile.
// A: f32 global->regs issued BEFORE compute (T14 issue-early), cvt+ds_write
//    into buf^1 AFTER the MFMA block (write-late), swizzled LDS chunks.
// B: global_load_lds with source-side pre-swizzle into buf^1 (in flight
//    across the whole MFMA phase; barrier's vmcnt(0) drain completes it).
__global__ __launch_bounds__(256) void proj_kernel(
    const float* __restrict__ Xlt, const float* __restrict__ Xrt,
    const unsigned short* __restrict__ Wt, const float* __restrict__ diag,
    unsigned short* __restrict__ Pb) {
  __shared__ unsigned short As[2][128 * 64];  // 2 x 16 KB
  __shared__ unsigned short Bs[2][128 * 64];  // 2 x 16 KB
  int t = threadIdx.x;
  int lane = t & 63, wave = t >> 6;
  int wr = wave >> 1, wc = wave & 1;
  int l15 = lane & 15, l4 = lane >> 4;

  // XCD swizzle: xcd = bid%8 processes nt=0..7 consecutively for its mt
  int bid = (int)blockIdx.x;
  int x = bid & 7, k = bid >> 3;          // k in [0,512)
  int mt = ((k >> 3) << 3) + x;           // [0,512)
  int nt = k & 7;
  int isLt = (mt < 256);
  const float* X = isLt ? Xlt : Xrt;
  int rowbase = (isLt ? mt : mt - 256) << 7;  // row within source tensor
  int prow = mt << 7;                          // row in Pb
  int n0 = nt << 7;

  // per-thread staging descriptors (4 chunks of 16B bf16 = 32B f32)
  const float* asrc[4];
  int adst[4];            // swizzled ushort offset within an As buffer
  const unsigned short* bsrc[4];
  int bdst[4];            // linear ushort offset within a Bs buffer
#pragma unroll
  for (int i = 0; i < 4; ++i) {
    int c = i * 256 + t;
    int r = c >> 3, kc = c & 7;
    asrc[i] = &X[(size_t)(rowbase + r) * H_ + kc * 8];
    adst[i] = (r * 8 + (kc ^ (r & 7))) * 8;
    bsrc[i] = &Wt[(size_t)(n0 + r) * H_ + (kc ^ (r & 7)) * 8];
    bdst[i] = c * 8;
  }
  int swz0 = ((0 * 4 + l4) ^ (l15 & 7)) * 8;
  int swz1 = ((1 * 4 + l4) ^ (l15 & 7)) * 8;

  f32x4 acc[4][4] = {};
  float4 a0[4], a1[4];

  // ---- prologue: stage tile 0 into buf 0 ----
#pragma unroll
  for (int i = 0; i < 4; ++i) {
    const float* s = asrc[i];
    a0[i] = ((const float4*)s)[0];
    a1[i] = ((const float4*)s)[1];
    gld16(bsrc[i], &Bs[0][bdst[i]]);
  }
#pragma unroll
  for (int i = 0; i < 4; ++i) {
    bf16x8 v;
    v[0] = (short)cvtbf(a0[i].x); v[1] = (short)cvtbf(a0[i].y);
    v[2] = (short)cvtbf(a0[i].z); v[3] = (short)cvtbf(a0[i].w);
    v[4] = (short)cvtbf(a1[i].x); v[5] = (short)cvtbf(a1[i].y);
    v[6] = (short)cvtbf(a1[i].z); v[7] = (short)cvtbf(a1[i].w);
    *(bf16x8*)&As[0][adst[i]] = v;
  }
  __syncthreads();

  int cur = 0;
  for (int kt = 0; kt < H_ / 64; ++kt) {
    int nk0 = (kt + 1) * 64;
    bool more = (kt < H_ / 64 - 1);
    // issue next tile's loads (stay in flight across the MFMA block)
    if (more) {
#pragma unroll
      for (int i = 0; i < 4; ++i) {
        const float* s = asrc[i] + nk0;
        a0[i] = ((const float4*)s)[0];
        a1[i] = ((const float4*)s)[1];
        gld16(bsrc[i] + nk0, &Bs[cur ^ 1][bdst[i]]);
      }
    }
    // compute on buf[cur]
    const unsigned short* Ac = &As[cur][0];
    const unsigned short* Bc = &Bs[cur][0];
#pragma unroll
    for (int kk = 0; kk < 2; ++kk) {
      int sw = kk ? swz1 : swz0;
      bf16x8 aq[4], bq[4];
#pragma unroll
      for (int mi = 0; mi < 4; ++mi)
        aq[mi] = *(const bf16x8*)&Ac[(wr * 64 + mi * 16 + l15) * 64 + sw];
#pragma unroll
      for (int ni = 0; ni < 4; ++ni)
        bq[ni] = *(const bf16x8*)&Bc[(wc * 64 + ni * 16 + l15) * 64 + sw];
#pragma unroll
      for (int mi = 0; mi < 4; ++mi)
#pragma unroll
        for (int ni = 0; ni < 4; ++ni)
          acc[mi][ni] = __builtin_amdgcn_mfma_f32_16x16x32_bf16(aq[mi], bq[ni], acc[mi][ni], 0, 0, 0);
    }
    // write-late: cvt the prefetched A regs into buf^1 (compiler inserts vmcnt)
    if (more) {
#pragma unroll
      for (int i = 0; i < 4; ++i) {
        bf16x8 v;
        v[0] = (short)cvtbf(a0[i].x); v[1] = (short)cvtbf(a0[i].y);
        v[2] = (short)cvtbf(a0[i].z); v[3] = (short)cvtbf(a0[i].w);
        v[4] = (short)cvtbf(a1[i].x); v[5] = (short)cvtbf(a1[i].y);
        v[6] = (short)cvtbf(a1[i].z); v[7] = (short)cvtbf(a1[i].w);
        *(bf16x8*)&As[cur ^ 1][adst[i]] = v;
      }
    }
    __syncthreads();
    cur ^= 1;
  }

#pragma unroll
  for (int mi = 0; mi < 4; ++mi) {
#pragma unroll
    for (int ni = 0; ni < 4; ++ni) {
      int col = n0 + wc * 64 + ni * 16 + l15;
      float d = isLt ? diag[col] : 1.0f;
#pragma unroll
      for (int r = 0; r < 4; ++r) {
        int row = prow + wr * 64 + mi * 16 + l4 * 4 + r;
        Pb[(size_t)row * A_ + col] = f2bf(fast_tanh(acc[mi][ni][r]) * d);
      }
    }
  }
}

// ---------- K2: scores[b][l][r] = (Plt[b,l,:] . Prt[b,r,:]) * ml * mr ----------
__global__ __launch_bounds__(256) void score_kernel(
    const unsigned short* __restrict__ Plt, const unsigned short* __restrict__ Prt,
    const float* __restrict__ mask_lt, const float* __restrict__ mask_rt,
    float* __restrict__ out) {
  __shared__ unsigned short As[128 * 64];
  __shared__ unsigned short Bs[128 * 64];
  int t = threadIdx.x;
  int lane = t & 63, wave = t >> 6;
  int wr = wave >> 1, wc = wave & 1;
  int l15 = lane & 15, l4 = lane >> 4;

  int bid = (int)blockIdx.x;                 // 1024 blocks
  int x = bid & 7, k = bid >> 3;             // k in [0,128)
  int atile = x + 8 * (k >> 2);              // [0,256)
  int b = atile >> 2, tm = atile & 3, tn = k & 3;

  const unsigned short* Abase = Plt + (size_t)b * L_ * A_ + (size_t)(tm * 128) * A_;
  const unsigned short* Bbase = Prt + (size_t)b * L_ * A_ + (size_t)(tn * 128) * A_;

  const unsigned short* asrc[4];
  const unsigned short* bsrc[4];
  int dst[4];
#pragma unroll
  for (int i = 0; i < 4; ++i) {
    int c = i * 256 + t;
    int r = c >> 3, kc = c & 7;
    int sc = (kc ^ (r & 7)) * 8;
    asrc[i] = &Abase[(size_t)r * A_ + sc];
    bsrc[i] = &Bbase[(size_t)r * A_ + sc];
    dst[i] = c * 8;
  }
  int swz0 = ((0 * 4 + l4) ^ (l15 & 7)) * 8;
  int swz1 = ((1 * 4 + l4) ^ (l15 & 7)) * 8;

  f32x4 acc[4][4] = {};
  for (int kt = 0; kt < A_ / 64; ++kt) {
    int k0 = kt * 64;
    __syncthreads();
#pragma unroll
    for (int i = 0; i < 4; ++i) {
      gld16(asrc[i] + k0, &As[dst[i]]);
      gld16(bsrc[i] + k0, &Bs[dst[i]]);
    }
    __syncthreads();
#pragma unroll
    for (int kk = 0; kk < 2; ++kk) {
      int sw = kk ? swz1 : swz0;
      bf16x8 aq[4], bq[4];
#pragma unroll
      for (int mi = 0; mi < 4; ++mi)
        aq[mi] = *(const bf16x8*)&As[(wr * 64 + mi * 16 + l15) * 64 + sw];
#pragma unroll
      for (int ni = 0; ni < 4; ++ni)
        bq[ni] = *(const bf16x8*)&Bs[(wc * 64 + ni * 16 + l15) * 64 + sw];
#pragma unroll
      for (int mi = 0; mi < 4; ++mi)
#pragma unroll
        for (int ni = 0; ni < 4; ++ni)
          acc[mi][ni] = __builtin_amdgcn_mfma_f32_16x16x32_bf16(aq[mi], bq[ni], acc[mi][ni], 0, 0, 0);
    }
  }
  const float* mlp = mask_lt + b * L_;
  const float* mrp = mask_rt + b * L_;
  float* obase = out + (size_t)b * L_ * L_;
#pragma unroll
  for (int mi = 0; mi < 4; ++mi) {
#pragma unroll
    for (int ni = 0; ni < 4; ++ni) {
      int col = tn * 128 + wc * 64 + ni * 16 + l15;
      float mr = mrp[col];
#pragma unroll
      for (int r = 0; r < 4; ++r) {
        int row = tm * 128 + wr * 64 + mi * 16 + l4 * 4 + r;
        obase[(size_t)row * L_ + col] = acc[mi][ni][r] * mlp[row] * mr;
      }
    }
  }
}

// ---------- K3: in-place row softmax over 512, then re-mask ----------
__global__ __launch_bounds__(256) void softmax_kernel(float* __restrict__ out,
                                                      const float* __restrict__ mask_lt,
                                                      const float* __restrict__ mask_rt) {
  int lane = threadIdx.x & 63, wave = threadIdx.x >> 6;
  int row = (int)blockIdx.x * 4 + wave;  // 0..32767
  int b = row >> 9;
  float* p = out + (size_t)row * L_;
  float4 v0 = *(const float4*)(p + lane * 8);
  float4 v1 = *(const float4*)(p + lane * 8 + 4);
  float m = fmaxf(fmaxf(fmaxf(v0.x, v0.y), fmaxf(v0.z, v0.w)),
                  fmaxf(fmaxf(v1.x, v1.y), fmaxf(v1.z, v1.w)));
#pragma unroll
  for (int off = 32; off; off >>= 1) m = fmaxf(m, __shfl_xor(m, off));
  float e0 = __expf(v0.x - m), e1 = __expf(v0.y - m), e2 = __expf(v0.z - m), e3 = __expf(v0.w - m);
  float e4 = __expf(v1.x - m), e5 = __expf(v1.y - m), e6 = __expf(v1.z - m), e7 = __expf(v1.w - m);
  float s = ((e0 + e1) + (e2 + e3)) + ((e4 + e5) + (e6 + e7));
#pragma unroll
  for (int off = 32; off; off >>= 1) s += __shfl_xor(s, off);
  float sc = (1.0f / s) * mask_lt[row];
  const float* mrp = mask_rt + (b << 9) + lane * 8;
  float4 mr0 = *(const float4*)mrp;
  float4 mr1 = *(const float4*)(mrp + 4);
  float4 o0 = make_float4(e0 * sc * mr0.x, e1 * sc * mr0.y, e2 * sc * mr0.z, e3 * sc * mr0.w);
  float4 o1 = make_float4(e4 * sc * mr1.x, e5 * sc * mr1.y, e6 * sc * mr1.z, e7 * sc * mr1.w);
  *(float4*)(p + lane * 8) = o0;
  *(float4*)(p + lane * 8 + 4) = o1;
}

extern "C" void kernel_launch(void* const* d_in, const int* in_sizes, int n_in,
                              void* d_out, int out_size, void* d_ws, size_t ws_size,
                              hipStream_t stream) {
  const float* reps_lt = (const float*)d_in[0];
  const float* reps_rt = (const float*)d_in[1];
  const float* mask_lt = (const float*)d_in[2];
  const float* mask_rt = (const float*)d_in[3];
  const float* attn_w1 = (const float*)d_in[4];
  const float* diag    = (const float*)d_in[5];
  float* out = (float*)d_out;

  unsigned short* wt  = (unsigned short*)d_ws;       // 2 MB
  unsigned short* pb  = wt + (size_t)H_ * A_;        // 128 MB
  unsigned short* plt = pb;
  unsigned short* prt = pb + (size_t)B_ * L_ * A_;

  hipLaunchKernelGGL(wtrans_kernel, dim3(1024), dim3(256), 0, stream, attn_w1, wt);
  hipLaunchKernelGGL(proj_kernel, dim3(4096), dim3(256), 0, stream,
                     reps_lt, reps_rt, wt, diag, pb);
  hipLaunchKernelGGL(score_kernel, dim3(1024), dim3(256), 0, stream,
                     plt, prt, mask_lt, mask_rt, out);
  hipLaunchKernelGGL(softmax_kernel, dim3(8192), dim3(256), 0, stream,
                     out, mask_lt, mask_rt);
}

// Round 5
// 341.304 us; speedup vs baseline: 1.2433x; 1.2433x over previous
//
#include <hip/hip_runtime.h>
#include <hip/hip_bf16.h>

#define B_ 64
#define L_ 512
#define H_ 1024
#define A_ 1024

typedef short bf16x8 __attribute__((ext_vector_type(8)));
typedef float f32x4 __attribute__((ext_vector_type(4)));

__device__ __forceinline__ void gld16(const void* g, void* l) {
  __builtin_amdgcn_global_load_lds((const __attribute__((address_space(1))) void*)g,
                                   (__attribute__((address_space(3))) void*)l, 16, 0, 0);
}

// f32 -> bf16 RNE bit trick (cold paths)
__device__ __forceinline__ unsigned short f2bf(float f) {
  unsigned u = __builtin_bit_cast(unsigned, f);
  u = (u + 0x7fffu + ((u >> 16) & 1u)) >> 16;
  return (unsigned short)u;
}

// hot-path cast: compiler fuses pairs into v_cvt_pk_bf16_f32
__device__ __forceinline__ unsigned short cvtbf(float f) {
  __hip_bfloat16 b = __float2bfloat16(f);
  return __builtin_bit_cast(unsigned short, b);
}

// tanh(x) = 1 - 2/(exp(2x)+1) with fast rcp (~1ulp, invisible in bf16)
__device__ __forceinline__ float fast_tanh(float x) {
  float e = __expf(2.f * x);
  float r = __builtin_amdgcn_rcpf(e + 1.f);
  return __builtin_fmaf(-2.f, r, 1.f);
}

// ---------- K-1: Xb = bf16(concat(Xlt, Xrt)), streaming ----------
__global__ __launch_bounds__(256) void cvt_kernel(const float* __restrict__ lt,
                                                  const float* __restrict__ rt,
                                                  unsigned short* __restrict__ xb) {
  const size_t NC = (size_t)B_ * L_ * H_ / 8;  // chunks per tensor
  size_t stride = (size_t)gridDim.x * blockDim.x;
  for (size_t c = (size_t)blockIdx.x * blockDim.x + threadIdx.x; c < 2 * NC; c += stride) {
    const float* src = (c < NC) ? (lt + c * 8) : (rt + (c - NC) * 8);
    float4 v0 = ((const float4*)src)[0];
    float4 v1 = ((const float4*)src)[1];
    bf16x8 o;
    o[0] = (short)cvtbf(v0.x); o[1] = (short)cvtbf(v0.y);
    o[2] = (short)cvtbf(v0.z); o[3] = (short)cvtbf(v0.w);
    o[4] = (short)cvtbf(v1.x); o[5] = (short)cvtbf(v1.y);
    o[6] = (short)cvtbf(v1.z); o[7] = (short)cvtbf(v1.w);
    *(bf16x8*)(xb + c * 8) = o;
  }
}

// ---------- K0: Wt[a][h] = bf16(W[h][a]) ----------
__global__ __launch_bounds__(256) void wtrans_kernel(const float* __restrict__ W,
                                                     unsigned short* __restrict__ Wt) {
  __shared__ float tile[32][33];
  int tx = threadIdx.x & 31, ty = threadIdx.x >> 5;  // 32 x 8
  int a0 = (blockIdx.x & 31) << 5, h0 = (blockIdx.x >> 5) << 5;
#pragma unroll
  for (int i = 0; i < 4; ++i) {
    int h = ty + i * 8;
    tile[h][tx] = W[(size_t)(h0 + h) * A_ + a0 + tx];
  }
  __syncthreads();
#pragma unroll
  for (int i = 0; i < 4; ++i) {
    int a = ty + i * 8;
    Wt[(size_t)(a0 + a) * H_ + h0 + tx] = f2bf(tile[tx][a]);
  }
}

// ---------- K1: 256x256 deep-pipelined proj: Pb = bf16(tanh(Xb@Wt^T)[*diag]) ----------
// 512 threads = 8 waves (2Mx4N), BK=64, dbuf LDS 128KB, counted vmcnt(8),
// raw s_barrier (no drain), 4 MFMA quadrant-phases with setprio.
__global__ __launch_bounds__(512, 2) void proj8_kernel(
    const unsigned short* __restrict__ Xb, const unsigned short* __restrict__ Wt,
    const float* __restrict__ diag, unsigned short* __restrict__ Pb) {
  __shared__ unsigned short As[2][256 * 64];  // 2 x 32 KB
  __shared__ unsigned short Bs[2][256 * 64];  // 2 x 32 KB
  int t = threadIdx.x;                 // 0..511
  int lane = t & 63, wave = t >> 6;
  int wr = wave >> 2, wcn = wave & 3;  // wave grid 2M x 4N, each 128x64 out
  int l15 = lane & 15, l4 = lane >> 4;

  // XCD swizzle: each XCD runs 4 consecutive N-tiles of one M-tile
  int bid = (int)blockIdx.x;           // 1024 blocks
  int x = bid & 7, k = bid >> 3;       // k in [0,128)
  int mt = x + 8 * (k >> 2);           // [0,256)
  int nt = k & 3;                      // [0,4)
  int mrow0 = mt << 8;
  int ncol0 = nt << 8;
  int isLt = (mt < 128);

  // staging: thread t handles rows r0 + {0,64,128,192}, chunk (t&7), src pre-swizzled
  int r0 = t >> 3;                               // 0..63
  int swzc = (((t & 7) ^ (r0 & 7)) << 3);        // swizzled chunk elem offset
  const unsigned short* A0 = Xb + (size_t)(mrow0 + r0) * H_ + swzc;
  const unsigned short* B0 = Wt + (size_t)(ncol0 + r0) * H_ + swzc;

#define STAGE(buf, koff)                                                   \
  {                                                                        \
    _Pragma("unroll") for (int i = 0; i < 4; ++i) {                        \
      gld16(A0 + (size_t)i * 64 * H_ + (koff), &As[buf][(i * 512 + t) * 8]); \
      gld16(B0 + (size_t)i * 64 * H_ + (koff), &Bs[buf][(i * 512 + t) * 8]); \
    }                                                                      \
  }

  f32x4 acc[8][4] = {};
  int rdsw0 = ((0 * 4 + l4) ^ (l15 & 7)) * 8;  // kk=0 read swizzle
  int rdsw1 = ((1 * 4 + l4) ^ (l15 & 7)) * 8;  // kk=1

  STAGE(0, 0);
  int cur = 0;
  for (int kt = 0; kt < 16; ++kt) {
    if (kt < 15) {
      STAGE(cur ^ 1, (kt + 1) * 64);
      asm volatile("s_waitcnt vmcnt(8)" ::: "memory");  // buf[cur] ready; new 8 in flight
    } else {
      asm volatile("s_waitcnt vmcnt(0)" ::: "memory");
    }
    asm volatile("s_barrier" ::: "memory");

    const unsigned short* Ac = As[cur];
    const unsigned short* Bc = Bs[cur];
    // B fragments for all 4 N-frags x 2 k-slices (reused by all 4 phases)
    bf16x8 bq[4][2];
#pragma unroll
    for (int ni = 0; ni < 4; ++ni) {
      int brow = wcn * 64 + ni * 16 + l15;
      bq[ni][0] = *(const bf16x8*)&Bc[brow * 64 + rdsw0];
      bq[ni][1] = *(const bf16x8*)&Bc[brow * 64 + rdsw1];
    }
#pragma unroll
    for (int ph = 0; ph < 4; ++ph) {
      bf16x8 aq[2][2];
#pragma unroll
      for (int m2 = 0; m2 < 2; ++m2) {
        int arow = wr * 128 + (ph * 2 + m2) * 16 + l15;
        aq[m2][0] = *(const bf16x8*)&Ac[arow * 64 + rdsw0];
        aq[m2][1] = *(const bf16x8*)&Ac[arow * 64 + rdsw1];
      }
      __builtin_amdgcn_s_setprio(1);
#pragma unroll
      for (int m2 = 0; m2 < 2; ++m2)
#pragma unroll
        for (int ni = 0; ni < 4; ++ni) {
          acc[ph * 2 + m2][ni] = __builtin_amdgcn_mfma_f32_16x16x32_bf16(
              aq[m2][0], bq[ni][0], acc[ph * 2 + m2][ni], 0, 0, 0);
          acc[ph * 2 + m2][ni] = __builtin_amdgcn_mfma_f32_16x16x32_bf16(
              aq[m2][1], bq[ni][1], acc[ph * 2 + m2][ni], 0, 0, 0);
        }
      __builtin_amdgcn_s_setprio(0);
    }
    asm volatile("s_barrier" ::: "memory");
    cur ^= 1;
  }
#undef STAGE

#pragma unroll
  for (int mi = 0; mi < 8; ++mi) {
#pragma unroll
    for (int ni = 0; ni < 4; ++ni) {
      int col = ncol0 + wcn * 64 + ni * 16 + l15;
      float d = isLt ? diag[col] : 1.0f;
#pragma unroll
      for (int rr = 0; rr < 4; ++rr) {
        int row = mrow0 + wr * 128 + mi * 16 + l4 * 4 + rr;
        Pb[(size_t)row * A_ + col] = f2bf(fast_tanh(acc[mi][ni][rr]) * d);
      }
    }
  }
}

// ---------- K2: scores[b][l][r] = (Plt[b,l,:] . Prt[b,r,:]) * ml * mr ----------
__global__ __launch_bounds__(256) void score_kernel(
    const unsigned short* __restrict__ Plt, const unsigned short* __restrict__ Prt,
    const float* __restrict__ mask_lt, const float* __restrict__ mask_rt,
    float* __restrict__ out) {
  __shared__ unsigned short As[128 * 64];
  __shared__ unsigned short Bs[128 * 64];
  int t = threadIdx.x;
  int lane = t & 63, wave = t >> 6;
  int wr = wave >> 1, wc = wave & 1;
  int l15 = lane & 15, l4 = lane >> 4;

  int bid = (int)blockIdx.x;                 // 1024 blocks
  int x = bid & 7, k = bid >> 3;             // k in [0,128)
  int atile = x + 8 * (k >> 2);              // [0,256)
  int b = atile >> 2, tm = atile & 3, tn = k & 3;

  const unsigned short* Abase = Plt + (size_t)b * L_ * A_ + (size_t)(tm * 128) * A_;
  const unsigned short* Bbase = Prt + (size_t)b * L_ * A_ + (size_t)(tn * 128) * A_;

  const unsigned short* asrc[4];
  const unsigned short* bsrc[4];
  int dst[4];
#pragma unroll
  for (int i = 0; i < 4; ++i) {
    int c = i * 256 + t;
    int r = c >> 3, kc = c & 7;
    int sc = (kc ^ (r & 7)) * 8;
    asrc[i] = &Abase[(size_t)r * A_ + sc];
    bsrc[i] = &Bbase[(size_t)r * A_ + sc];
    dst[i] = c * 8;
  }
  int swz0 = ((0 * 4 + l4) ^ (l15 & 7)) * 8;
  int swz1 = ((1 * 4 + l4) ^ (l15 & 7)) * 8;

  f32x4 acc[4][4] = {};
  for (int kt = 0; kt < A_ / 64; ++kt) {
    int k0 = kt * 64;
    __syncthreads();
#pragma unroll
    for (int i = 0; i < 4; ++i) {
      gld16(asrc[i] + k0, &As[dst[i]]);
      gld16(bsrc[i] + k0, &Bs[dst[i]]);
    }
    __syncthreads();
#pragma unroll
    for (int kk = 0; kk < 2; ++kk) {
      int sw = kk ? swz1 : swz0;
      bf16x8 aq[4], bq[4];
#pragma unroll
      for (int mi = 0; mi < 4; ++mi)
        aq[mi] = *(const bf16x8*)&As[(wr * 64 + mi * 16 + l15) * 64 + sw];
#pragma unroll
      for (int ni = 0; ni < 4; ++ni)
        bq[ni] = *(const bf16x8*)&Bs[(wc * 64 + ni * 16 + l15) * 64 + sw];
#pragma unroll
      for (int mi = 0; mi < 4; ++mi)
#pragma unroll
        for (int ni = 0; ni < 4; ++ni)
          acc[mi][ni] = __builtin_amdgcn_mfma_f32_16x16x32_bf16(aq[mi], bq[ni], acc[mi][ni], 0, 0, 0);
    }
  }
  const float* mlp = mask_lt + b * L_;
  const float* mrp = mask_rt + b * L_;
  float* obase = out + (size_t)b * L_ * L_;
#pragma unroll
  for (int mi = 0; mi < 4; ++mi) {
#pragma unroll
    for (int ni = 0; ni < 4; ++ni) {
      int col = tn * 128 + wc * 64 + ni * 16 + l15;
      float mr = mrp[col];
#pragma unroll
      for (int r = 0; r < 4; ++r) {
        int row = tm * 128 + wr * 64 + mi * 16 + l4 * 4 + r;
        obase[(size_t)row * L_ + col] = acc[mi][ni][r] * mlp[row] * mr;
      }
    }
  }
}

// ---------- K3: in-place row softmax over 512, then re-mask ----------
__global__ __launch_bounds__(256) void softmax_kernel(float* __restrict__ out,
                                                      const float* __restrict__ mask_lt,
                                                      const float* __restrict__ mask_rt) {
  int lane = threadIdx.x & 63, wave = threadIdx.x >> 6;
  int row = (int)blockIdx.x * 4 + wave;  // 0..32767
  int b = row >> 9;
  float* p = out + (size_t)row * L_;
  float4 v0 = *(const float4*)(p + lane * 8);
  float4 v1 = *(const float4*)(p + lane * 8 + 4);
  float m = fmaxf(fmaxf(fmaxf(v0.x, v0.y), fmaxf(v0.z, v0.w)),
                  fmaxf(fmaxf(v1.x, v1.y), fmaxf(v1.z, v1.w)));
#pragma unroll
  for (int off = 32; off; off >>= 1) m = fmaxf(m, __shfl_xor(m, off));
  float e0 = __expf(v0.x - m), e1 = __expf(v0.y - m), e2 = __expf(v0.z - m), e3 = __expf(v0.w - m);
  float e4 = __expf(v1.x - m), e5 = __expf(v1.y - m), e6 = __expf(v1.z - m), e7 = __expf(v1.w - m);
  float s = ((e0 + e1) + (e2 + e3)) + ((e4 + e5) + (e6 + e7));
#pragma unroll
  for (int off = 32; off; off >>= 1) s += __shfl_xor(s, off);
  float sc = (1.0f / s) * mask_lt[row];
  const float* mrp = mask_rt + (b << 9) + lane * 8;
  float4 mr0 = *(const float4*)mrp;
  float4 mr1 = *(const float4*)(mrp + 4);
  float4 o0 = make_float4(e0 * sc * mr0.x, e1 * sc * mr0.y, e2 * sc * mr0.z, e3 * sc * mr0.w);
  float4 o1 = make_float4(e4 * sc * mr1.x, e5 * sc * mr1.y, e6 * sc * mr1.z, e7 * sc * mr1.w);
  *(float4*)(p + lane * 8) = o0;
  *(float4*)(p + lane * 8 + 4) = o1;
}

extern "C" void kernel_launch(void* const* d_in, const int* in_sizes, int n_in,
                              void* d_out, int out_size, void* d_ws, size_t ws_size,
                              hipStream_t stream) {
  const float* reps_lt = (const float*)d_in[0];
  const float* reps_rt = (const float*)d_in[1];
  const float* mask_lt = (const float*)d_in[2];
  const float* mask_rt = (const float*)d_in[3];
  const float* attn_w1 = (const float*)d_in[4];
  const float* diag    = (const float*)d_in[5];
  float* out = (float*)d_out;

  unsigned short* wt  = (unsigned short*)d_ws;       // 2 MB
  unsigned short* pb  = wt + (size_t)H_ * A_;        // 128 MB
  unsigned short* xb  = pb + (size_t)B_ * L_ * A_ * 2;  // 128 MB (ws >= 258MB, verified R3)
  unsigned short* plt = pb;
  unsigned short* prt = pb + (size_t)B_ * L_ * A_;

  hipLaunchKernelGGL(wtrans_kernel, dim3(1024), dim3(256), 0, stream, attn_w1, wt);
  hipLaunchKernelGGL(cvt_kernel, dim3(8192), dim3(256), 0, stream,
                     reps_lt, reps_rt, xb);
  hipLaunchKernelGGL(proj8_kernel, dim3(1024), dim3(512), 0, stream,
                     xb, wt, diag, pb);
  hipLaunchKernelGGL(score_kernel, dim3(1024), dim3(256), 0, stream,
                     plt, prt, mask_lt, mask_rt, out);
  hipLaunchKernelGGL(softmax_kernel, dim3(8192), dim3(256), 0, stream,
                     out, mask_lt, mask_rt);
}